// Round 13
// baseline (96.602 us; speedup 1.0000x reference)
//
#include <hip/hip_runtime.h>
#include <math.h>

#define NB 4
#define NS 256
#define NV 200
#define NF 4
#define NG 80
#define NFG 320
#define NROT 16
#define DELTA_F 0.39269908169872414f      // 2pi/16
#define INV_DELTA_F 2.5464790894703254f   // 16/2pi

#define SLOTS 248        // afe columns
#define TT_STRIDE 252    // Tt columns
#define T_ROWS 31
#define D_ROW 27         // f32, odd stride -> conflict-light reads

#define AFE_OFF   15632
#define AFE_BYTES 12400
#define X_OFF     27648
#define AUX_WCNT  30608
#define AUX_BASE  30768
#define AUX_GRPQ  30836
#define SMEM_BYTES 30912
#define ZERO_BYTES 28032
#define TT_BYTES  15632

// per-patch cache in d_ws (rho/theta/mask-derived data, identical across launches)
#define CRM  15632
#define CSL  23568
#define CGQ  24016
#define CNS  24080
#define CST  24192

#define WT_ELEMS  (4 * 3 * 5 * 64 * 8)   // 30720 (f, ks, wv-tile, lane, 8 elems)
#define D1T_ELEMS (NFG * NG)             // 25600: d1t[t][i] = d1_w[(part*80+i)*80+h]

typedef __attribute__((ext_vector_type(8))) short short8v;   // 8 bf16
typedef __attribute__((ext_vector_type(4))) float floatx4;   // MFMA acc
typedef __attribute__((ext_vector_type(4))) unsigned int uintx4;

__device__ __forceinline__ short8v mk_frag(unsigned a, unsigned b, unsigned c, unsigned d) {
    uintx4 v = {a, b, c, d};
    return __builtin_bit_cast(short8v, v);
}
__device__ __forceinline__ unsigned short rne_bf16(float v) {
    const unsigned u = __float_as_uint(v);
    return (unsigned short)((u + 0x7fffu + ((u >> 16) & 1u)) >> 16);
}

// Pre-pack W fragments in MFMA lane order + transposed d1 weights.
__global__ __launch_bounds__(256) void prep_w_kernel(
    const float* __restrict__ W, const float* __restrict__ d1w,
    unsigned short* __restrict__ Wh, unsigned short* __restrict__ Wl,
    float* __restrict__ d1t)
{
    const int G = blockIdx.x * 256 + threadIdx.x;
    if (G < WT_ELEMS) {
        const int e    = G & 7;
        const int lane = (G >> 3) & 63;
        int rest = G >> 9;
        const int wvt = rest % 5;  rest /= 5;
        const int ks  = rest % 3;
        const int f   = rest / 3;
        const int g   = ks * 32 + (lane >> 4) * 8 + e;
        const int h   = 16 * wvt + (lane & 15);
        float v = 0.0f;
        if (g < NG) v = W[((size_t)(f * NG + g)) * NG + h];
        const unsigned u  = __float_as_uint(v);
        const unsigned hb = u & 0xffff0000u;
        const float    lo = v - __uint_as_float(hb);
        Wh[G] = (unsigned short)(u >> 16);
        Wl[G] = (unsigned short)(__float_as_uint(lo) >> 16);
    } else if (G < WT_ELEMS + D1T_ELEMS && d1t != nullptr) {
        const int e2   = G - WT_ELEMS;
        const int tt   = e2 / NG;          // destination thread 0..319
        const int i2   = e2 - tt * NG;     // 0..79
        const int part = tt / NG;
        const int h    = tt - part * NG;
        d1t[e2] = d1w[(size_t)(part * NG + i2) * NG + h];
    }
}

template<int MODE>
__global__ __launch_bounds__(NFG, 6) void masif_block_kernel(
    const float* __restrict__ input_feat,
    const float* __restrict__ rho,
    const float* __restrict__ theta,
    const float* __restrict__ mask,
    const float* __restrict__ mu_rho,
    const float* __restrict__ sigma_rho,
    const float* __restrict__ sigma_theta,
    const float* __restrict__ W_conv,
    const unsigned short* __restrict__ Wt_h,
    const unsigned short* __restrict__ Wt_l,
    const float* __restrict__ d1t,
    char* __restrict__ cacheb,
    const float* __restrict__ b_conv,
    const float* __restrict__ bn_gamma,
    const float* __restrict__ bn_beta,
    const float* __restrict__ bn_mean,
    const float* __restrict__ bn_var,
    const float* __restrict__ d1_w,
    const float* __restrict__ d1_b,
    const float* __restrict__ d2_w,
    const float* __restrict__ d2_b,
    const float* __restrict__ d3_w,
    const float* __restrict__ d3_b,
    const float* __restrict__ out_w,
    const float* __restrict__ out_b,
    const int*   __restrict__ indices,
    const float* __restrict__ x_in,
    float*       __restrict__ x_out)
{
    const int bs = blockIdx.x;
    const int t  = threadIdx.x;
    const int lane = t & 63;
    const int lr   = lane & 15;
    const int lk   = lane >> 4;
    const int wv   = t >> 6;

    __shared__ __align__(16) char smem[SMEM_BYTES];

    unsigned short* Tt     = (unsigned short*)smem;
    unsigned short* afe_h  = (unsigned short*)(smem + AFE_OFF);
    float*          D_s    = (float*)smem;
    float*          x_s    = (float*)(smem + X_OFF);
    float*          y1p    = x_s + NFG;
    float*          y1_s   = y1p + NFG;
    float*          y2_s   = y1_s + NG;
    float*          y3_s   = y2_s + NF;
    unsigned short* wcnt16 = (unsigned short*)(smem + AUX_WCNT);
    unsigned int*   base_s = (unsigned int*)(smem + AUX_BASE);
    unsigned char*  grpq   = (unsigned char*)(smem + AUX_GRPQ);

    const int base = bs * NV;
    const int b    = bs / NS;
    char* cb = cacheb ? cacheb + (size_t)bs * CST : nullptr;
    const bool valid = (t < NV);

    if (MODE == 0 || cb == nullptr) {
        const float sr  = sigma_rho[0];
        const float st  = sigma_theta[0];
        const float isr = 1.0f / (sr * sr + 1e-5f);
        const float ist = 1.0f / (st * st + 1e-5f);

        for (int off = t * 16; off < ZERO_BYTES; off += NFG * 16)
            *(uintx4*)(smem + off) = (uintx4){0u, 0u, 0u, 0u};

        float rv = 0.0f, mv = 0.0f, thv = 0.0f, av = 0.0f;
        float4 fv = {0.f, 0.f, 0.f, 0.f};
        int myq = 0, rank = 0, slot = 0;
        float Rreg[5];
        if (valid) {
            rv  = rho[base + t];
            mv  = mask[base + t];
            thv = theta[base + t];
            if (MODE == 0) {
                fv = *reinterpret_cast<const float4*>(&input_feat[(size_t)(base + t) * NF]);
            } else {
                const int idx = indices[base + t];
                fv = *reinterpret_cast<const float4*>(&x_in[(size_t)(b * NS + idx) * NF]);
            }
            const float qf = floorf(thv * INV_DELTA_F);
            av  = fmaf(-qf, DELTA_F, thv);
            myq = ((int)qf) & 15;
        }
        {
            unsigned long long mymask = 0ull;
            #pragma unroll
            for (int bq = 0; bq < 16; ++bq) {
                const unsigned long long m = __ballot(valid && (myq == bq));
                if (lane == bq) wcnt16[wv * 16 + bq] = (unsigned short)__popcll(m);
                if (valid && myq == bq) mymask = m;
            }
            rank = (int)__popcll(mymask & ((1ull << lane) - 1ull));
        }
        __syncthreads();

        if (t < 16) {   // parallel padded prefix
            unsigned c = 0;
            #pragma unroll
            for (int w = 0; w < 5; ++w) c += wcnt16[w * 16 + t];
            c = (c + 3u) & ~3u;
            unsigned s = c;
            #pragma unroll
            for (int off = 1; off < 16; off <<= 1) {
                const unsigned n = __shfl_up(s, off, 16);
                if (t >= off) s += n;
            }
            base_s[t] = s - c;
            if (t == 15) base_s[16] = s;
        }
        __syncthreads();

        if (valid) {
            int rk = rank;
            #pragma unroll
            for (int w = 0; w < 3; ++w)
                if (wv > w) rk += wcnt16[w * 16 + myq];
            slot = (int)base_s[myq] + rk;

            const float fvl[5] = {1.0f, fv.x, fv.y, fv.z, fv.w};
            #pragma unroll
            for (int ri = 0; ri < 5; ++ri) {
                const float dr = rv - mu_rho[ri * 16];
                Rreg[ri] = mv * __expf(-(dr * dr) * isr);
                #pragma unroll
                for (int fp = 0; fp < 5; ++fp)
                    afe_h[(fp * 5 + ri) * SLOTS + slot] = rne_bf16(fvl[fp] * Rreg[ri]);
            }
            const float gb1 = __expf(-ist * DELTA_F * DELTA_F);
            const float gb2 = gb1 * gb1;
            const float E2  = __expf(-2.0f * av * DELTA_F * ist);
            const float E2i = __builtin_amdgcn_rcpf(E2);
            const float f0  = __expf(-(av * av) * ist);
            Tt[15 * TT_STRIDE + slot] = rne_bf16(f0);
            float f = f0, h = E2 * gb1;
            #pragma unroll 5
            for (int k = 0; k < 15; ++k) {
                f *= h; h *= gb2;
                Tt[(16 + k) * TT_STRIDE + slot] = rne_bf16(f);
            }
            f = f0; h = E2i * gb1;
            #pragma unroll 5
            for (int k = 0; k < 15; ++k) {
                f *= h; h *= gb2;
                Tt[(14 - k) * TT_STRIDE + slot] = rne_bf16(f);
            }
        }
        if (t < 64) {
            const unsigned g4 = (unsigned)(t * 4);
            int qq = 0;
            #pragma unroll
            for (int bq = 0; bq < 16; ++bq)
                if (g4 >= base_s[bq] && g4 < base_s[bq + 1]) qq = bq;
            grpq[t] = (unsigned char)qq;
        }
        __syncthreads();

        if (MODE == 0 && cb != nullptr) {
            for (int off = t * 16; off < TT_BYTES; off += NFG * 16)
                *(uintx4*)(cb + off) = *(const uintx4*)(smem + off);
            if (valid) {
                float* RmG = (float*)(cb + CRM) + slot * 8;
                #pragma unroll
                for (int ri = 0; ri < 5; ++ri) RmG[ri] = Rreg[ri];
                ((unsigned short*)(cb + CSL))[t] = (unsigned short)slot;
            }
            if (t < 64) ((unsigned char*)(cb + CGQ))[t] = grpq[t];
            if (t == 0) *(unsigned int*)(cb + CNS) = base_s[16];
        }
    } else {
        for (int off = AFE_OFF + t * 16; off < AFE_OFF + AFE_BYTES; off += NFG * 16)
            *(uintx4*)(smem + off) = (uintx4){0u, 0u, 0u, 0u};
        for (int off = t * 16; off < TT_BYTES; off += NFG * 16)
            *(uintx4*)(smem + off) = *(const uintx4*)(cb + off);
        if (t < 64) grpq[t] = ((const unsigned char*)(cb + CGQ))[t];
        if (t == 0) base_s[16] = *(const unsigned int*)(cb + CNS);

        int slot = 0;
        float4 fv = {0.f, 0.f, 0.f, 0.f};
        float Rm0 = 0.f, Rm1 = 0.f, Rm2 = 0.f, Rm3 = 0.f, Rm4 = 0.f;
        if (valid) {
            const int idx = indices[base + t];
            fv = *reinterpret_cast<const float4*>(&x_in[(size_t)(b * NS + idx) * NF]);
            slot = ((const unsigned short*)(cb + CSL))[t];
            const float* RmG = (const float*)(cb + CRM) + slot * 8;
            const float4 r4 = *reinterpret_cast<const float4*>(RmG);
            Rm0 = r4.x; Rm1 = r4.y; Rm2 = r4.z; Rm3 = r4.w; Rm4 = RmG[4];
        }
        __syncthreads();
        if (valid) {
            const float fvl[5] = {1.0f, fv.x, fv.y, fv.z, fv.w};
            const float Rm[5] = {Rm0, Rm1, Rm2, Rm3, Rm4};
            #pragma unroll
            for (int ri = 0; ri < 5; ++ri)
                #pragma unroll
                for (int fp = 0; fp < 5; ++fp)
                    afe_h[(fp * 5 + ri) * SLOTS + slot] = rne_bf16(fvl[fp] * Rm[ri]);
        }
        __syncthreads();
    }

    // ---- stage 1 ----
    floatx4 acc[8];
    #pragma unroll
    for (int ci = 0; ci < 8; ++ci) acc[ci] = floatx4{0.f, 0.f, 0.f, 0.f};

    const int nslot = (int)base_s[16];
    const int rhi   = 16 + (lr < 9 ? lr : 8);

    #pragma unroll 2
    for (int kb = 0; kb < 8; ++kb) {
        const int  s0     = kb * 32 + 8 * lk;
        const bool anyout = (kb * 32 + 32) > nslot;
        int vb0 = s0;
        bool h0 = true, h1 = true;
        if (anyout) {
            h0  = s0 < nslot;
            h1  = (s0 + 4) < nslot;
            vb0 = h0 ? s0 : 0;
        }
        const int g0 = vb0 >> 2;
        const unsigned qa = grpq[g0];
        const unsigned qb = grpq[g0 + 1];

        short8v bh0 = *(const short8v*)&afe_h[lr * SLOTS + vb0];
        short8v bh1 = *(const short8v*)&afe_h[rhi * SLOTS + vb0];
        if (lr >= 9) bh1 = (short8v){0,0,0,0,0,0,0,0};
        if (anyout) {
            uintx4 u0 = __builtin_bit_cast(uintx4, bh0);
            uintx4 u2 = __builtin_bit_cast(uintx4, bh1);
            if (!h0) { u0.x=0; u0.y=0; u2.x=0; u2.y=0; }
            if (!h1) { u0.z=0; u0.w=0; u2.z=0; u2.w=0; }
            bh0 = __builtin_bit_cast(short8v, u0);
            bh1 = __builtin_bit_cast(short8v, u2);
        }

        #pragma unroll
        for (int mi = 0; mi < 4; ++mi) {
            const int mt = wv + 5 * mi;
            if (mt < 16) {
                const int da = 15 - lr + (int)((qa + (unsigned)mt) & 15u);
                const int db = 15 - lr + (int)((qb + (unsigned)mt) & 15u);
                const uint2 alo = *(const uint2*)&Tt[da * TT_STRIDE + vb0];
                const uint2 ahi = *(const uint2*)&Tt[db * TT_STRIDE + vb0 + 4];
                const short8v ah = mk_frag(alo.x, alo.y, ahi.x, ahi.y);
                acc[2 * mi]     = __builtin_amdgcn_mfma_f32_16x16x32_bf16(ah, bh0, acc[2 * mi],     0, 0, 0);
                acc[2 * mi + 1] = __builtin_amdgcn_mfma_f32_16x16x32_bf16(ah, bh1, acc[2 * mi + 1], 0, 0, 0);
            }
        }
    }
    __syncthreads();

    // ---- write D_s ----
    #pragma unroll
    for (int mi = 0; mi < 4; ++mi) {
        const int mt = wv + 5 * mi;
        if (mt < 16) {
            #pragma unroll
            for (int nt = 0; nt < 2; ++nt) {
                const int i = 16 * nt + lr;
                if (i < 25) {
                    #pragma unroll
                    for (int q = 0; q < 4; ++q) {
                        const int ti = 4 * lk + q;
                        D_s[(ti * 16 + mt) * D_ROW + i] = acc[2 * mi + nt][q];
                    }
                }
            }
        }
    }
    __syncthreads();

    // ---- stage 3 + fused bias/BN/relu ----
    {
        const int hcol = 16 * wv + lr;
        const bool useWt = (Wt_h != nullptr);
        floatx4 acc2[4];
        #pragma unroll
        for (int f = 0; f < 4; ++f) acc2[f] = floatx4{0.f, 0.f, 0.f, 0.f};

        #pragma unroll
        for (int ks = 0; ks < 3; ++ks) {
            const int g0 = ks * 32 + 8 * lk;
            float rden[8];
            #pragma unroll
            for (int e = 0; e < 8; ++e) {
                const int g = g0 + e;
                if (g < NG) {
                    const int ti = g & 15, ri = g >> 4;
                    rden[e] = __builtin_amdgcn_rcpf(D_s[(ti * 16 + lr) * D_ROW + ri] + 1e-5f);
                } else rden[e] = 0.0f;
            }
            #pragma unroll
            for (int f = 0; f < 4; ++f) {
                short8v wfh, wfl;
                if (useWt) {
                    const size_t wo = ((size_t)(((f * 3 + ks) * 5 + wv) * 64 + lane)) * 8;
                    wfh = *(const short8v*)&Wt_h[wo];
                    wfl = *(const short8v*)&Wt_l[wo];
                } else {
                    unsigned wh[4], wl[4];
                    #pragma unroll
                    for (int w2 = 0; w2 < 4; ++w2) {
                        const int ga = g0 + 2 * w2, gb = ga + 1;
                        float v0 = 0.f, v1 = 0.f;
                        if (ga < NG) v0 = W_conv[((size_t)(f * NG + ga)) * NG + hcol];
                        if (gb < NG) v1 = W_conv[((size_t)(f * NG + gb)) * NG + hcol];
                        const unsigned ua  = __float_as_uint(v0);
                        const unsigned ha  = ua & 0xffff0000u;
                        const float    la  = v0 - __uint_as_float(ha);
                        const unsigned ub  = __float_as_uint(v1);
                        const unsigned hb2 = ub & 0xffff0000u;
                        const float    lb  = v1 - __uint_as_float(hb2);
                        wh[w2] = (ua >> 16) | hb2;
                        wl[w2] = (__float_as_uint(la) >> 16) | (__float_as_uint(lb) & 0xffff0000u);
                    }
                    wfh = mk_frag(wh[0], wh[1], wh[2], wh[3]);
                    wfl = mk_frag(wl[0], wl[1], wl[2], wl[3]);
                }
                unsigned dh[4], dl[4];
                #pragma unroll
                for (int w2 = 0; w2 < 4; ++w2) {
                    float pv[2];
                    #pragma unroll
                    for (int p = 0; p < 2; ++p) {
                        const int e = 2 * w2 + p;
                        const int g = g0 + e;
                        float dv = 0.0f;
                        if (g < NG) {
                            const int ti = g & 15, ri = g >> 4;
                            dv = D_s[(ti * 16 + lr) * D_ROW + (f + 1) * 5 + ri] * rden[e];
                        }
                        pv[p] = dv;
                    }
                    const unsigned ua = __float_as_uint(pv[0]);
                    const unsigned ha = ua & 0xffff0000u;
                    const float    la = pv[0] - __uint_as_float(ha);
                    const unsigned ub = __float_as_uint(pv[1]);
                    const unsigned hb2 = ub & 0xffff0000u;
                    const float    lb = pv[1] - __uint_as_float(hb2);
                    dh[w2] = (ua >> 16) | hb2;
                    dl[w2] = (__float_as_uint(la) >> 16) | (__float_as_uint(lb) & 0xffff0000u);
                }
                const short8v dhv = mk_frag(dh[0], dh[1], dh[2], dh[3]);
                const short8v dlv = mk_frag(dl[0], dl[1], dl[2], dl[3]);
                acc2[f] = __builtin_amdgcn_mfma_f32_16x16x32_bf16(dhv, wfh, acc2[f], 0, 0, 0);
                acc2[f] = __builtin_amdgcn_mfma_f32_16x16x32_bf16(dhv, wfl, acc2[f], 0, 0, 0);
                acc2[f] = __builtin_amdgcn_mfma_f32_16x16x32_bf16(dlv, wfh, acc2[f], 0, 0, 0);
            }
        }
        __syncthreads();
        #pragma unroll
        for (int f = 0; f < 4; ++f) {
            float mx = fmaxf(fmaxf(acc2[f][0], acc2[f][1]), fmaxf(acc2[f][2], acc2[f][3]));
            mx = fmaxf(mx, __shfl_xor(mx, 16));
            mx = fmaxf(mx, __shfl_xor(mx, 32));
            if (lk == 0) {
                const int idx = f * NG + hcol;
                const float cm = mx + b_conv[idx];
                const float xv = (cm - bn_mean[idx]) * rsqrtf(bn_var[idx] + 1e-3f) * bn_gamma[idx] + bn_beta[idx];
                x_s[idx] = fmaxf(xv, 0.0f);
            }
        }
    }
    __syncthreads();

    // ---- d1: 320->80 relu (4 partials x 80 h); transposed weights if available ----
    {
        const int part = t / NG;
        const int h    = t - part * NG;
        const int ib   = part * NG;
        float a = 0.0f;
        if (d1t != nullptr) {
            const float4* wr = (const float4*)(d1t + (size_t)t * NG);
            const float4* xr = (const float4*)(x_s + ib);
            #pragma unroll 5
            for (int k = 0; k < NG / 4; ++k) {
                const float4 w4 = wr[k];
                const float4 x4 = xr[k];
                a = fmaf(x4.x, w4.x, a); a = fmaf(x4.y, w4.y, a);
                a = fmaf(x4.z, w4.z, a); a = fmaf(x4.w, w4.w, a);
            }
        } else {
            #pragma unroll 8
            for (int i2 = 0; i2 < NG; ++i2)
                a = fmaf(x_s[ib + i2], d1_w[(size_t)(ib + i2) * NG + h], a);
        }
        y1p[part * NG + h] = a;
    }
    __syncthreads();
    if (t < NG) {
        const float a = d1_b[t] + y1p[t] + y1p[NG + t] + y1p[2 * NG + t] + y1p[3 * NG + t];
        y1_s[t] = fmaxf(a, 0.0f);
    }
    __syncthreads();

    // ---- d2: 80->4 relu ----
    if (t < NF) {
        float a = d2_b[t];
        #pragma unroll 8
        for (int i = 0; i < NG; ++i)
            a = fmaf(y1_s[i], d2_w[(size_t)i * NF + t], a);
        a = fmaxf(a, 0.0f);
        if (MODE < 2) x_out[(size_t)bs * NF + t] = a;
        else          y2_s[t] = a;
    }

    if (MODE == 2) {
        __syncthreads();
        if (t < 16) {
            float a = d3_b[t];
            #pragma unroll
            for (int ff = 0; ff < NF; ++ff)
                a = fmaf(y2_s[ff], d3_w[ff * 16 + t], a);
            y3_s[t] = fmaxf(a, 0.0f);
        }
        __syncthreads();
        if (t == 0) {
            float a = out_b[0];
            #pragma unroll
            for (int k = 0; k < 16; ++k)
                a = fmaf(y3_s[k], out_w[k], a);
            x_out[bs] = a;
        }
    }
}

extern "C" void kernel_launch(void* const* d_in, const int* in_sizes, int n_in,
                              void* d_out, int out_size, void* d_ws, size_t ws_size,
                              hipStream_t stream) {
    const float* input_feat  = (const float*)d_in[0];
    const float* rho         = (const float*)d_in[1];
    const float* theta       = (const float*)d_in[2];
    const float* mask        = (const float*)d_in[3];
    const float* mu_rho      = (const float*)d_in[4];
    const float* sigma_rho   = (const float*)d_in[6];
    const float* sigma_theta = (const float*)d_in[7];
    const float* W_conv      = (const float*)d_in[8];
    const float* b_conv      = (const float*)d_in[9];
    const float* bn_gamma    = (const float*)d_in[10];
    const float* bn_beta     = (const float*)d_in[11];
    const float* bn_mean     = (const float*)d_in[12];
    const float* bn_var      = (const float*)d_in[13];
    const float* d1_w        = (const float*)d_in[14];
    const float* d1_b        = (const float*)d_in[15];
    const float* d2_w        = (const float*)d_in[16];
    const float* d2_b        = (const float*)d_in[17];
    const float* d3_w        = (const float*)d_in[18];
    const float* d3_b        = (const float*)d_in[19];
    const float* out_w       = (const float*)d_in[20];
    const float* out_b       = (const float*)d_in[21];
    const int*   indices     = (const int*)d_in[22];

    float* x1  = (float*)d_ws;                 // [4096] f32
    float* x2  = x1 + (size_t)NB * NS * NF;    // [4096] f32
    float* out = (float*)d_out;

    const size_t WT_OFF   = 32768;
    const size_t WT_BYTES = (size_t)2 * WT_ELEMS * 2;           // 122880
    const size_t CACHE_OFF = 163840;
    const size_t CACHE_BYTES = (size_t)NB * NS * CST;           // ~24.8 MB
    const size_t D1T_OFF  = 27262976;                           // 26 MB, past cache end
    const size_t D1T_BYTES = (size_t)D1T_ELEMS * 4;             // 102400

    unsigned short* Wh = nullptr;
    unsigned short* Wl = nullptr;
    float* d1t = nullptr;
    if (ws_size >= WT_OFF + WT_BYTES) {
        Wh = (unsigned short*)((char*)d_ws + WT_OFF);
        Wl = Wh + WT_ELEMS;
    }
    if (ws_size >= D1T_OFF + D1T_BYTES) {
        d1t = (float*)((char*)d_ws + D1T_OFF);
    }
    if (Wh != nullptr) {
        const int total = WT_ELEMS + D1T_ELEMS;
        prep_w_kernel<<<(total + 255) / 256, 256, 0, stream>>>(W_conv, d1_w, Wh, Wl, d1t);
    }

    char* cacheb = nullptr;
    if (ws_size >= CACHE_OFF + CACHE_BYTES) {
        cacheb = (char*)d_ws + CACHE_OFF;
    }

    dim3 grid(NB * NS), block(NFG);

    masif_block_kernel<0><<<grid, block, 0, stream>>>(
        input_feat, rho, theta, mask, mu_rho, sigma_rho, sigma_theta,
        W_conv, Wh, Wl, d1t, cacheb, b_conv, bn_gamma, bn_beta, bn_mean, bn_var,
        d1_w, d1_b, d2_w, d2_b, d3_w, d3_b, out_w, out_b, indices, nullptr, x1);

    masif_block_kernel<1><<<grid, block, 0, stream>>>(
        input_feat, rho, theta, mask, mu_rho, sigma_rho, sigma_theta,
        W_conv, Wh, Wl, d1t, cacheb, b_conv, bn_gamma, bn_beta, bn_mean, bn_var,
        d1_w, d1_b, d2_w, d2_b, d3_w, d3_b, out_w, out_b, indices, x1, x2);

    masif_block_kernel<2><<<grid, block, 0, stream>>>(
        input_feat, rho, theta, mask, mu_rho, sigma_rho, sigma_theta,
        W_conv, Wh, Wl, d1t, cacheb, b_conv, bn_gamma, bn_beta, bn_mean, bn_var,
        d1_w, d1_b, d2_w, d2_b, d3_w, d3_b, out_w, out_b, indices, x2, out);
}

// Round 14
// 80.975 us; speedup vs baseline: 1.1930x; 1.1930x over previous
//
#include <hip/hip_runtime.h>
#include <math.h>

#define NB 4
#define NS 256
#define NV 200
#define NF 4
#define NG 80
#define NFG 320
#define NROT 16
#define DELTA_F 0.39269908169872414f      // 2pi/16
#define INV_DELTA_F 2.5464790894703254f   // 16/2pi

#define SLOTS 248        // afe columns
#define TT_STRIDE 252    // Tt columns
#define T_ROWS 31
#define D_ROW 27         // f32, odd stride -> conflict-light reads

#define AFE_OFF   15632
#define AFE_BYTES 12400
#define X_OFF     27648
#define AUX_WCNT  30608
#define AUX_BASE  30768
#define AUX_GRPQ  30836
#define SMEM_BYTES 30912
#define ZERO_BYTES 28032
#define TT_BYTES  15632

// per-patch cache in d_ws (rho/theta/mask-derived data, identical across launches)
#define CRM  15632
#define CSL  23568
#define CGQ  24016
#define CNS  24080
#define CST  24192

#define WT_ELEMS (4 * 3 * 5 * 64 * 8)   // 30720 (f, ks, wv-tile, lane, 8 elems)

typedef __attribute__((ext_vector_type(8))) short short8v;   // 8 bf16
typedef __attribute__((ext_vector_type(4))) float floatx4;   // MFMA acc
typedef __attribute__((ext_vector_type(4))) unsigned int uintx4;

__device__ __forceinline__ short8v mk_frag(unsigned a, unsigned b, unsigned c, unsigned d) {
    uintx4 v = {a, b, c, d};
    return __builtin_bit_cast(short8v, v);
}
__device__ __forceinline__ unsigned short rne_bf16(float v) {
    const unsigned u = __float_as_uint(v);
    return (unsigned short)((u + 0x7fffu + ((u >> 16) & 1u)) >> 16);
}

// Pre-pack W fragments in exact MFMA lane order:
// Wh/Wl[(((f*3+ks)*5+wvt)*64+lane)*8+e] = bf16 of W[f][g][h], g=ks*32+(lane>>4)*8+e, h=16*wvt+(lane&15)
__global__ __launch_bounds__(256) void prep_w_kernel(
    const float* __restrict__ W, unsigned short* __restrict__ Wh, unsigned short* __restrict__ Wl)
{
    const int G = blockIdx.x * 256 + threadIdx.x;
    if (G >= WT_ELEMS) return;
    const int e    = G & 7;
    const int lane = (G >> 3) & 63;
    int rest = G >> 9;
    const int wvt = rest % 5;  rest /= 5;
    const int ks  = rest % 3;
    const int f   = rest / 3;
    const int g   = ks * 32 + (lane >> 4) * 8 + e;
    const int h   = 16 * wvt + (lane & 15);
    float v = 0.0f;
    if (g < NG) v = W[((size_t)(f * NG + g)) * NG + h];
    const unsigned u  = __float_as_uint(v);
    const unsigned hb = u & 0xffff0000u;
    const float    lo = v - __uint_as_float(hb);
    Wh[G] = (unsigned short)(u >> 16);
    Wl[G] = (unsigned short)(__float_as_uint(lo) >> 16);
}

template<int MODE>
__global__ __launch_bounds__(NFG, 6) void masif_block_kernel(
    const float* __restrict__ input_feat,
    const float* __restrict__ rho,
    const float* __restrict__ theta,
    const float* __restrict__ mask,
    const float* __restrict__ mu_rho,
    const float* __restrict__ sigma_rho,
    const float* __restrict__ sigma_theta,
    const float* __restrict__ W_conv,
    const unsigned short* __restrict__ Wt_h,
    const unsigned short* __restrict__ Wt_l,
    char* __restrict__ cacheb,
    const float* __restrict__ b_conv,
    const float* __restrict__ bn_gamma,
    const float* __restrict__ bn_beta,
    const float* __restrict__ bn_mean,
    const float* __restrict__ bn_var,
    const float* __restrict__ d1_w,
    const float* __restrict__ d1_b,
    const float* __restrict__ d2_w,
    const float* __restrict__ d2_b,
    const float* __restrict__ d3_w,
    const float* __restrict__ d3_b,
    const float* __restrict__ out_w,
    const float* __restrict__ out_b,
    const int*   __restrict__ indices,
    const float* __restrict__ x_in,
    float*       __restrict__ x_out)
{
    const int bs = blockIdx.x;
    const int t  = threadIdx.x;
    const int lane = t & 63;
    const int lr   = lane & 15;
    const int lk   = lane >> 4;
    const int wv   = t >> 6;

    __shared__ __align__(16) char smem[SMEM_BYTES];

    unsigned short* Tt     = (unsigned short*)smem;
    unsigned short* afe_h  = (unsigned short*)(smem + AFE_OFF);
    float*          D_s    = (float*)smem;
    float*          x_s    = (float*)(smem + X_OFF);
    float*          y1p    = x_s + NFG;
    float*          y1_s   = y1p + NFG;
    float*          y2_s   = y1_s + NG;
    float*          y3_s   = y2_s + NF;
    unsigned short* wcnt16 = (unsigned short*)(smem + AUX_WCNT);
    unsigned int*   base_s = (unsigned int*)(smem + AUX_BASE);
    unsigned char*  grpq   = (unsigned char*)(smem + AUX_GRPQ);

    const int base = bs * NV;
    const int b    = bs / NS;
    char* cb = cacheb ? cacheb + (size_t)bs * CST : nullptr;
    const bool valid = (t < NV);

    if (MODE == 0 || cb == nullptr) {
        const float sr  = sigma_rho[0];
        const float st  = sigma_theta[0];
        const float isr = 1.0f / (sr * sr + 1e-5f);
        const float ist = 1.0f / (st * st + 1e-5f);

        for (int off = t * 16; off < ZERO_BYTES; off += NFG * 16)
            *(uintx4*)(smem + off) = (uintx4){0u, 0u, 0u, 0u};

        float rv = 0.0f, mv = 0.0f, thv = 0.0f, av = 0.0f;
        float4 fv = {0.f, 0.f, 0.f, 0.f};
        int myq = 0, rank = 0, slot = 0;
        float Rreg[5];
        if (valid) {
            rv  = rho[base + t];
            mv  = mask[base + t];
            thv = theta[base + t];
            if (MODE == 0) {
                fv = *reinterpret_cast<const float4*>(&input_feat[(size_t)(base + t) * NF]);
            } else {
                const int idx = indices[base + t];
                fv = *reinterpret_cast<const float4*>(&x_in[(size_t)(b * NS + idx) * NF]);
            }
            const float qf = floorf(thv * INV_DELTA_F);
            av  = fmaf(-qf, DELTA_F, thv);
            myq = ((int)qf) & 15;
        }
        {
            unsigned long long mymask = 0ull;
            #pragma unroll
            for (int bq = 0; bq < 16; ++bq) {
                const unsigned long long m = __ballot(valid && (myq == bq));
                if (lane == bq) wcnt16[wv * 16 + bq] = (unsigned short)__popcll(m);
                if (valid && myq == bq) mymask = m;
            }
            rank = (int)__popcll(mymask & ((1ull << lane) - 1ull));
        }
        __syncthreads();

        if (t < 16) {   // parallel padded prefix
            unsigned c = 0;
            #pragma unroll
            for (int w = 0; w < 5; ++w) c += wcnt16[w * 16 + t];
            c = (c + 3u) & ~3u;
            unsigned s = c;
            #pragma unroll
            for (int off = 1; off < 16; off <<= 1) {
                const unsigned n = __shfl_up(s, off, 16);
                if (t >= off) s += n;
            }
            base_s[t] = s - c;
            if (t == 15) base_s[16] = s;
        }
        __syncthreads();

        if (valid) {
            int rk = rank;
            #pragma unroll
            for (int w = 0; w < 3; ++w)
                if (wv > w) rk += wcnt16[w * 16 + myq];
            slot = (int)base_s[myq] + rk;

            const float fvl[5] = {1.0f, fv.x, fv.y, fv.z, fv.w};
            #pragma unroll
            for (int ri = 0; ri < 5; ++ri) {
                const float dr = rv - mu_rho[ri * 16];
                Rreg[ri] = mv * __expf(-(dr * dr) * isr);
                #pragma unroll
                for (int fp = 0; fp < 5; ++fp)
                    afe_h[(fp * 5 + ri) * SLOTS + slot] = rne_bf16(fvl[fp] * Rreg[ri]);
            }
            const float gb1 = __expf(-ist * DELTA_F * DELTA_F);
            const float gb2 = gb1 * gb1;
            const float E2  = __expf(-2.0f * av * DELTA_F * ist);
            const float E2i = __builtin_amdgcn_rcpf(E2);
            const float f0  = __expf(-(av * av) * ist);
            Tt[15 * TT_STRIDE + slot] = rne_bf16(f0);
            float f = f0, h = E2 * gb1;
            #pragma unroll 5
            for (int k = 0; k < 15; ++k) {
                f *= h; h *= gb2;
                Tt[(16 + k) * TT_STRIDE + slot] = rne_bf16(f);
            }
            f = f0; h = E2i * gb1;
            #pragma unroll 5
            for (int k = 0; k < 15; ++k) {
                f *= h; h *= gb2;
                Tt[(14 - k) * TT_STRIDE + slot] = rne_bf16(f);
            }
        }
        if (t < 64) {
            const unsigned g4 = (unsigned)(t * 4);
            int qq = 0;
            #pragma unroll
            for (int bq = 0; bq < 16; ++bq)
                if (g4 >= base_s[bq] && g4 < base_s[bq + 1]) qq = bq;
            grpq[t] = (unsigned char)qq;
        }
        __syncthreads();

        if (MODE == 0 && cb != nullptr) {
            for (int off = t * 16; off < TT_BYTES; off += NFG * 16)
                *(uintx4*)(cb + off) = *(const uintx4*)(smem + off);
            if (valid) {
                float* RmG = (float*)(cb + CRM) + slot * 8;
                #pragma unroll
                for (int ri = 0; ri < 5; ++ri) RmG[ri] = Rreg[ri];
                ((unsigned short*)(cb + CSL))[t] = (unsigned short)slot;
            }
            if (t < 64) ((unsigned char*)(cb + CGQ))[t] = grpq[t];
            if (t == 0) *(unsigned int*)(cb + CNS) = base_s[16];
        }
    } else {
        for (int off = AFE_OFF + t * 16; off < AFE_OFF + AFE_BYTES; off += NFG * 16)
            *(uintx4*)(smem + off) = (uintx4){0u, 0u, 0u, 0u};
        for (int off = t * 16; off < TT_BYTES; off += NFG * 16)
            *(uintx4*)(smem + off) = *(const uintx4*)(cb + off);
        if (t < 64) grpq[t] = ((const unsigned char*)(cb + CGQ))[t];
        if (t == 0) base_s[16] = *(const unsigned int*)(cb + CNS);

        int slot = 0;
        float4 fv = {0.f, 0.f, 0.f, 0.f};
        float Rm0 = 0.f, Rm1 = 0.f, Rm2 = 0.f, Rm3 = 0.f, Rm4 = 0.f;
        if (valid) {
            const int idx = indices[base + t];
            fv = *reinterpret_cast<const float4*>(&x_in[(size_t)(b * NS + idx) * NF]);
            slot = ((const unsigned short*)(cb + CSL))[t];
            const float* RmG = (const float*)(cb + CRM) + slot * 8;
            const float4 r4 = *reinterpret_cast<const float4*>(RmG);
            Rm0 = r4.x; Rm1 = r4.y; Rm2 = r4.z; Rm3 = r4.w; Rm4 = RmG[4];
        }
        __syncthreads();
        if (valid) {
            const float fvl[5] = {1.0f, fv.x, fv.y, fv.z, fv.w};
            const float Rm[5] = {Rm0, Rm1, Rm2, Rm3, Rm4};
            #pragma unroll
            for (int ri = 0; ri < 5; ++ri)
                #pragma unroll
                for (int fp = 0; fp < 5; ++fp)
                    afe_h[(fp * 5 + ri) * SLOTS + slot] = rne_bf16(fvl[fp] * Rm[ri]);
        }
        __syncthreads();
    }

    // ---- stage 1 ----
    floatx4 acc[8];
    #pragma unroll
    for (int ci = 0; ci < 8; ++ci) acc[ci] = floatx4{0.f, 0.f, 0.f, 0.f};

    const int nslot = (int)base_s[16];
    const int rhi   = 16 + (lr < 9 ? lr : 8);

    #pragma unroll 2
    for (int kb = 0; kb < 8; ++kb) {
        const int  s0     = kb * 32 + 8 * lk;
        const bool anyout = (kb * 32 + 32) > nslot;
        int vb0 = s0;
        bool h0 = true, h1 = true;
        if (anyout) {
            h0  = s0 < nslot;
            h1  = (s0 + 4) < nslot;
            vb0 = h0 ? s0 : 0;
        }
        const int g0 = vb0 >> 2;
        const unsigned qa = grpq[g0];
        const unsigned qb = grpq[g0 + 1];

        short8v bh0 = *(const short8v*)&afe_h[lr * SLOTS + vb0];
        short8v bh1 = *(const short8v*)&afe_h[rhi * SLOTS + vb0];
        if (lr >= 9) bh1 = (short8v){0,0,0,0,0,0,0,0};
        if (anyout) {
            uintx4 u0 = __builtin_bit_cast(uintx4, bh0);
            uintx4 u2 = __builtin_bit_cast(uintx4, bh1);
            if (!h0) { u0.x=0; u0.y=0; u2.x=0; u2.y=0; }
            if (!h1) { u0.z=0; u0.w=0; u2.z=0; u2.w=0; }
            bh0 = __builtin_bit_cast(short8v, u0);
            bh1 = __builtin_bit_cast(short8v, u2);
        }

        __builtin_amdgcn_s_setprio(1);
        #pragma unroll
        for (int mi = 0; mi < 4; ++mi) {
            const int mt = wv + 5 * mi;
            if (mt < 16) {
                const int da = 15 - lr + (int)((qa + (unsigned)mt) & 15u);
                const int db = 15 - lr + (int)((qb + (unsigned)mt) & 15u);
                const uint2 alo = *(const uint2*)&Tt[da * TT_STRIDE + vb0];
                const uint2 ahi = *(const uint2*)&Tt[db * TT_STRIDE + vb0 + 4];
                const short8v ah = mk_frag(alo.x, alo.y, ahi.x, ahi.y);
                acc[2 * mi]     = __builtin_amdgcn_mfma_f32_16x16x32_bf16(ah, bh0, acc[2 * mi],     0, 0, 0);
                acc[2 * mi + 1] = __builtin_amdgcn_mfma_f32_16x16x32_bf16(ah, bh1, acc[2 * mi + 1], 0, 0, 0);
            }
        }
        __builtin_amdgcn_s_setprio(0);
    }
    __syncthreads();

    // ---- write D_s ----
    #pragma unroll
    for (int mi = 0; mi < 4; ++mi) {
        const int mt = wv + 5 * mi;
        if (mt < 16) {
            #pragma unroll
            for (int nt = 0; nt < 2; ++nt) {
                const int i = 16 * nt + lr;
                if (i < 25) {
                    #pragma unroll
                    for (int q = 0; q < 4; ++q) {
                        const int ti = 4 * lk + q;
                        D_s[(ti * 16 + mt) * D_ROW + i] = acc[2 * mi + nt][q];
                    }
                }
            }
        }
    }
    __syncthreads();

    // ---- stage 3 + fused bias/BN/relu ----
    {
        const int hcol = 16 * wv + lr;
        const bool useWt = (Wt_h != nullptr);
        floatx4 acc2[4];
        #pragma unroll
        for (int f = 0; f < 4; ++f) acc2[f] = floatx4{0.f, 0.f, 0.f, 0.f};

        #pragma unroll
        for (int ks = 0; ks < 3; ++ks) {
            const int g0 = ks * 32 + 8 * lk;
            float rden[8];
            #pragma unroll
            for (int e = 0; e < 8; ++e) {
                const int g = g0 + e;
                if (g < NG) {
                    const int ti = g & 15, ri = g >> 4;
                    rden[e] = __builtin_amdgcn_rcpf(D_s[(ti * 16 + lr) * D_ROW + ri] + 1e-5f);
                } else rden[e] = 0.0f;
            }
            #pragma unroll
            for (int f = 0; f < 4; ++f) {
                short8v wfh, wfl;
                if (useWt) {
                    const size_t wo = ((size_t)(((f * 3 + ks) * 5 + wv) * 64 + lane)) * 8;
                    wfh = *(const short8v*)&Wt_h[wo];
                    wfl = *(const short8v*)&Wt_l[wo];
                } else {
                    unsigned wh[4], wl[4];
                    #pragma unroll
                    for (int w2 = 0; w2 < 4; ++w2) {
                        const int ga = g0 + 2 * w2, gb = ga + 1;
                        float v0 = 0.f, v1 = 0.f;
                        if (ga < NG) v0 = W_conv[((size_t)(f * NG + ga)) * NG + hcol];
                        if (gb < NG) v1 = W_conv[((size_t)(f * NG + gb)) * NG + hcol];
                        const unsigned ua  = __float_as_uint(v0);
                        const unsigned ha  = ua & 0xffff0000u;
                        const float    la  = v0 - __uint_as_float(ha);
                        const unsigned ub  = __float_as_uint(v1);
                        const unsigned hb2 = ub & 0xffff0000u;
                        const float    lb  = v1 - __uint_as_float(hb2);
                        wh[w2] = (ua >> 16) | hb2;
                        wl[w2] = (__float_as_uint(la) >> 16) | (__float_as_uint(lb) & 0xffff0000u);
                    }
                    wfh = mk_frag(wh[0], wh[1], wh[2], wh[3]);
                    wfl = mk_frag(wl[0], wl[1], wl[2], wl[3]);
                }
                unsigned dh[4], dl[4];
                #pragma unroll
                for (int w2 = 0; w2 < 4; ++w2) {
                    float pv[2];
                    #pragma unroll
                    for (int p = 0; p < 2; ++p) {
                        const int e = 2 * w2 + p;
                        const int g = g0 + e;
                        float dv = 0.0f;
                        if (g < NG) {
                            const int ti = g & 15, ri = g >> 4;
                            dv = D_s[(ti * 16 + lr) * D_ROW + (f + 1) * 5 + ri] * rden[e];
                        }
                        pv[p] = dv;
                    }
                    const unsigned ua = __float_as_uint(pv[0]);
                    const unsigned ha = ua & 0xffff0000u;
                    const float    la = pv[0] - __uint_as_float(ha);
                    const unsigned ub = __float_as_uint(pv[1]);
                    const unsigned hb2 = ub & 0xffff0000u;
                    const float    lb = pv[1] - __uint_as_float(hb2);
                    dh[w2] = (ua >> 16) | hb2;
                    dl[w2] = (__float_as_uint(la) >> 16) | (__float_as_uint(lb) & 0xffff0000u);
                }
                const short8v dhv = mk_frag(dh[0], dh[1], dh[2], dh[3]);
                const short8v dlv = mk_frag(dl[0], dl[1], dl[2], dl[3]);
                __builtin_amdgcn_s_setprio(1);
                acc2[f] = __builtin_amdgcn_mfma_f32_16x16x32_bf16(dhv, wfh, acc2[f], 0, 0, 0);
                acc2[f] = __builtin_amdgcn_mfma_f32_16x16x32_bf16(dhv, wfl, acc2[f], 0, 0, 0);
                acc2[f] = __builtin_amdgcn_mfma_f32_16x16x32_bf16(dlv, wfh, acc2[f], 0, 0, 0);
                __builtin_amdgcn_s_setprio(0);
            }
        }
        __syncthreads();
        #pragma unroll
        for (int f = 0; f < 4; ++f) {
            float mx = fmaxf(fmaxf(acc2[f][0], acc2[f][1]), fmaxf(acc2[f][2], acc2[f][3]));
            mx = fmaxf(mx, __shfl_xor(mx, 16));
            mx = fmaxf(mx, __shfl_xor(mx, 32));
            if (lk == 0) {
                const int idx = f * NG + hcol;
                const float cm = mx + b_conv[idx];
                const float xv = (cm - bn_mean[idx]) * rsqrtf(bn_var[idx] + 1e-3f) * bn_gamma[idx] + bn_beta[idx];
                x_s[idx] = fmaxf(xv, 0.0f);
            }
        }
    }
    __syncthreads();

    // ---- d1: 320->80 relu (4 partials x 80 h), coalesced original layout ----
    {
        const int part = t / NG;
        const int h    = t - part * NG;
        const int ib   = part * NG;
        float a = 0.0f;
        #pragma unroll 8
        for (int i2 = 0; i2 < NG; ++i2)
            a = fmaf(x_s[ib + i2], d1_w[(size_t)(ib + i2) * NG + h], a);
        y1p[part * NG + h] = a;
    }
    __syncthreads();
    if (t < NG) {
        const float a = d1_b[t] + y1p[t] + y1p[NG + t] + y1p[2 * NG + t] + y1p[3 * NG + t];
        y1_s[t] = fmaxf(a, 0.0f);
    }
    __syncthreads();

    // ---- d2: 80->4 relu ----
    if (t < NF) {
        float a = d2_b[t];
        #pragma unroll 8
        for (int i = 0; i < NG; ++i)
            a = fmaf(y1_s[i], d2_w[(size_t)i * NF + t], a);
        a = fmaxf(a, 0.0f);
        if (MODE < 2) x_out[(size_t)bs * NF + t] = a;
        else          y2_s[t] = a;
    }

    if (MODE == 2) {
        __syncthreads();
        if (t < 16) {
            float a = d3_b[t];
            #pragma unroll
            for (int ff = 0; ff < NF; ++ff)
                a = fmaf(y2_s[ff], d3_w[ff * 16 + t], a);
            y3_s[t] = fmaxf(a, 0.0f);
        }
        __syncthreads();
        if (t == 0) {
            float a = out_b[0];
            #pragma unroll
            for (int k = 0; k < 16; ++k)
                a = fmaf(y3_s[k], out_w[k], a);
            x_out[bs] = a;
        }
    }
}

extern "C" void kernel_launch(void* const* d_in, const int* in_sizes, int n_in,
                              void* d_out, int out_size, void* d_ws, size_t ws_size,
                              hipStream_t stream) {
    const float* input_feat  = (const float*)d_in[0];
    const float* rho         = (const float*)d_in[1];
    const float* theta       = (const float*)d_in[2];
    const float* mask        = (const float*)d_in[3];
    const float* mu_rho      = (const float*)d_in[4];
    const float* sigma_rho   = (const float*)d_in[6];
    const float* sigma_theta = (const float*)d_in[7];
    const float* W_conv      = (const float*)d_in[8];
    const float* b_conv      = (const float*)d_in[9];
    const float* bn_gamma    = (const float*)d_in[10];
    const float* bn_beta     = (const float*)d_in[11];
    const float* bn_mean     = (const float*)d_in[12];
    const float* bn_var      = (const float*)d_in[13];
    const float* d1_w        = (const float*)d_in[14];
    const float* d1_b        = (const float*)d_in[15];
    const float* d2_w        = (const float*)d_in[16];
    const float* d2_b        = (const float*)d_in[17];
    const float* d3_w        = (const float*)d_in[18];
    const float* d3_b        = (const float*)d_in[19];
    const float* out_w       = (const float*)d_in[20];
    const float* out_b       = (const float*)d_in[21];
    const int*   indices     = (const int*)d_in[22];

    float* x1  = (float*)d_ws;                 // [4096] f32
    float* x2  = x1 + (size_t)NB * NS * NF;    // [4096] f32
    float* out = (float*)d_out;

    const size_t WT_OFF   = 32768;
    const size_t WT_BYTES = (size_t)2 * WT_ELEMS * 2;   // 122880
    unsigned short* Wh = nullptr;
    unsigned short* Wl = nullptr;
    if (ws_size >= WT_OFF + WT_BYTES) {
        Wh = (unsigned short*)((char*)d_ws + WT_OFF);
        Wl = Wh + WT_ELEMS;
        prep_w_kernel<<<(WT_ELEMS + 255) / 256, 256, 0, stream>>>(W_conv, Wh, Wl);
    }

    const size_t CACHE_OFF = 163840;
    char* cacheb = nullptr;
    if (ws_size >= CACHE_OFF + (size_t)NB * NS * CST) {
        cacheb = (char*)d_ws + CACHE_OFF;
    }

    dim3 grid(NB * NS), block(NFG);

    masif_block_kernel<0><<<grid, block, 0, stream>>>(
        input_feat, rho, theta, mask, mu_rho, sigma_rho, sigma_theta,
        W_conv, Wh, Wl, cacheb, b_conv, bn_gamma, bn_beta, bn_mean, bn_var,
        d1_w, d1_b, d2_w, d2_b, d3_w, d3_b, out_w, out_b, indices, nullptr, x1);

    masif_block_kernel<1><<<grid, block, 0, stream>>>(
        input_feat, rho, theta, mask, mu_rho, sigma_rho, sigma_theta,
        W_conv, Wh, Wl, cacheb, b_conv, bn_gamma, bn_beta, bn_mean, bn_var,
        d1_w, d1_b, d2_w, d2_b, d3_w, d3_b, out_w, out_b, indices, x1, x2);

    masif_block_kernel<2><<<grid, block, 0, stream>>>(
        input_feat, rho, theta, mask, mu_rho, sigma_rho, sigma_theta,
        W_conv, Wh, Wl, cacheb, b_conv, bn_gamma, bn_beta, bn_mean, bn_var,
        d1_w, d1_b, d2_w, d2_b, d3_w, d3_b, out_w, out_b, indices, x2, out);
}